// Round 10
// baseline (167.906 us; speedup 1.0000x reference)
//
#include <hip/hip_runtime.h>
#include <math.h>

// Problem: B=16, LQ=1024, LK=1024, DK=256, DV=256, fp32 in/out, mask int32.
// Identity: softmax_k(q_s + k_s with mask) == mask-weighted softmax of k_s alone
// (q_s cancels; masked entries are exactly -1e9 -> weight 0). query never read.
// k_s ~ N(0,256) => softmax mass concentrates in top ~30-60 keys; chunk-0
// (top-64) provably terminates ~all rows (e_64 ~ e^-26 * Z << 1e-5 * Z).
//
// R1: bitonic sort -> counting-sort select.   R2 (FAIL 218us): scalar-chain.
// R3-R7 (50-62us): per-row walks latency-bound. R8 (FAIL 95us): reg pipeline
//   killed occupancy. R9 (44.6us attn, 159.8 total): 4 rows/wave LDS walk --
//   walk cheap (VALU 16%), but 4 mask GATHERS/wave (~40 scattered 64B lines
//   each) at 22% occupancy ran HBM at 13% efficiency: gather-in-low-occupancy
//   is the measured bottleneck.
// R10: split along that seam. bmz_kernel = pure streaming (4096 blocks, no
//   LDS/barriers): coalesced mask-row read (R6 pattern, ~5-6 TB/s like the
//   82%-BW fills), bpermute bit resolve, ballot -> bm u64, masked butterfly
//   -> Z; 12B/row out. attn_kernel = R9 minus gathers minus butterflies:
//   bm/Z as wave-uniform scalar loads, LDS-staged V, fixed-64 walk with
//   scalar-selected weights. attn HBM drops to V(1MB)+out(16.7MB)+metadata.

#define NB     16
#define NL     1024     // LQ == LK
#define ND     256      // DK == DV
#define NBKT   128      // buckets of width 1.0 in log-space

// ---------------- Kernel A: ks[b,k] = dot(key[b,k,:], w) -----------------
__global__ __launch_bounds__(256)
void ks_kernel(const float* __restrict__ key, const float* __restrict__ w,
               float* __restrict__ ks) {
    int wid  = threadIdx.x >> 6;
    int lane = threadIdx.x & 63;
    int row  = blockIdx.x * 4 + wid;               // 0 .. NB*NL-1
    const float4* krow = (const float4*)(key + (size_t)row * ND);
    float4 kv = krow[lane];
    float4 wv = ((const float4*)w)[lane];
    float p = kv.x * wv.x + kv.y * wv.y + kv.z * wv.z + kv.w * wv.w;
    #pragma unroll
    for (int off = 32; off > 0; off >>= 1)
        p += __shfl_xor(p, off, 64);
    if (lane == 0) ks[row] = p;
}

// ------- Kernel B: per batch: max, e=exp(ks-m), counting sort by -------
// ------- bucket floor(m-v), exact suffix mass at chunk boundaries -------
// 256 threads (4 waves), 4 entries/thread. Order within a bucket arbitrary;
// attn breaks on the EXACT suffix mass rem[] of the actual gathered order.
__global__ __launch_bounds__(256)
void select_kernel(const float* __restrict__ ks,
                   float2* __restrict__ pk, float* __restrict__ rem) {
    __shared__ float se[NL];       // gathered e values (bucket order)
    __shared__ int   cnt[NBKT];    // histogram
    __shared__ int   cur[NBKT];    // scan -> scatter cursors
    __shared__ float wred[4];      // per-wave max
    __shared__ float csum[16];     // per-chunk sums
    const int b    = blockIdx.x;
    const int t    = threadIdx.x;
    const int lane = t & 63;
    const int wid  = t >> 6;
    const float* ksb = ks + b * NL;

    if (t < NBKT) cnt[t] = 0;

    // 4 entries per thread, coalesced (stride 256)
    float v0 = ksb[t], v1 = ksb[t + 256], v2 = ksb[t + 512], v3 = ksb[t + 768];

    // block max: thread max4 -> wave shuffle reduce -> 4-way LDS combine
    float mx = fmaxf(fmaxf(v0, v1), fmaxf(v2, v3));
    #pragma unroll
    for (int off = 32; off > 0; off >>= 1)
        mx = fmaxf(mx, __shfl_xor(mx, off, 64));
    if (lane == 0) wred[wid] = mx;
    __syncthreads();                                        // #1 (also covers cnt=0)
    const float m = fmaxf(fmaxf(wred[0], wred[1]), fmaxf(wred[2], wred[3]));

    float e0 = __expf(v0 - m), e1 = __expf(v1 - m);
    float e2 = __expf(v2 - m), e3 = __expf(v3 - m);
    int b0 = (int)fminf(m - v0, (float)(NBKT - 1));
    int b1 = (int)fminf(m - v1, (float)(NBKT - 1));
    int b2 = (int)fminf(m - v2, (float)(NBKT - 1));
    int b3 = (int)fminf(m - v3, (float)(NBKT - 1));
    atomicAdd(&cnt[b0], 1); atomicAdd(&cnt[b1], 1);
    atomicAdd(&cnt[b2], 1); atomicAdd(&cnt[b3], 1);
    __syncthreads();                                        // #2

    // exclusive scan of cnt[128] by wave 0 via shuffles (no barriers inside)
    if (wid == 0) {
        int a  = cnt[lane];
        int b2v = cnt[lane + 64];
        int sa = a, sb = b2v;
        #pragma unroll
        for (int d = 1; d < 64; d <<= 1) {
            int na = __shfl_up(sa, d, 64);
            int nb = __shfl_up(sb, d, 64);
            if (lane >= d) { sa += na; sb += nb; }
        }
        int tot = __shfl(sa, 63, 64);
        sb += tot;
        cur[lane]      = sa - a;
        cur[lane + 64] = sb - b2v;
    }
    __syncthreads();                                        // #3

    // scatter (bijective: every entry gets a unique p in [0, NL))
    int p0 = atomicAdd(&cur[b0], 1);
    int p1 = atomicAdd(&cur[b1], 1);
    int p2 = atomicAdd(&cur[b2], 1);
    int p3 = atomicAdd(&cur[b3], 1);
    se[p0] = e0; pk[b * NL + p0] = make_float2(e0, __int_as_float(t));
    se[p1] = e1; pk[b * NL + p1] = make_float2(e1, __int_as_float(t + 256));
    se[p2] = e2; pk[b * NL + p2] = make_float2(e2, __int_as_float(t + 512));
    se[p3] = e3; pk[b * NL + p3] = make_float2(e3, __int_as_float(t + 768));
    __syncthreads();                                        // #4

    // per-chunk sums: wave w reduces chunks 4w..4w+3
    #pragma unroll
    for (int cc = 0; cc < 4; ++cc) {
        int chunk = wid * 4 + cc;
        float s = se[chunk * 64 + lane];
        #pragma unroll
        for (int off = 32; off > 0; off >>= 1)
            s += __shfl_xor(s, off, 64);
        if (lane == 0) csum[chunk] = s;
    }
    __syncthreads();                                        // #5

    // suffix masses at the 16 boundary slots attn actually reads
    if (t == 0) {
        float run = 0.0f;
        for (int c = 15; c >= 0; --c) {
            rem[b * NL + c * 64 + 63] = run;
            run += csum[c];
        }
    }
}

// ------- Kernel B2: per row: bm u64 (mask at batch top-64) and Z -------
// Pure streaming: 4 waves/block, 1 row/wave, coalesced 4KB mask-row read
// (R6's verified lane+64*j int4 pattern), no LDS arrays, no barriers.
__global__ __launch_bounds__(256)
void bmz_kernel(const int* __restrict__ mask, const float2* __restrict__ pk,
                unsigned long long* __restrict__ bmask,
                float* __restrict__ zrow) {
    const int wid  = threadIdx.x >> 6;
    const int lane = threadIdx.x & 63;
    const int row  = blockIdx.x * 4 + wid;    // 0 .. NB*NL-1
    const int b    = row >> 10;

    // lane i holds the batch's top-i (e, key index)
    float2 p0 = pk[(b << 10) + lane];
    float e0 = p0.x;
    int   k0 = __float_as_int(p0.y);

    // mask row, fully coalesced: load j covers columns 256j + 4*lane + (0..3)
    // lane's 16 bits: bit (4j + c) = column 256j + 4*lane + c
    const int4* mrow4 = (const int4*)(mask + (size_t)row * NL);
    unsigned int bits = 0;
    #pragma unroll
    for (int j = 0; j < 4; ++j) {
        int4 mm = mrow4[lane + 64 * j];
        bits |= (mm.x != 0 ? 1u : 0u) << (j * 4 + 0);
        bits |= (mm.y != 0 ? 1u : 0u) << (j * 4 + 1);
        bits |= (mm.z != 0 ? 1u : 0u) << (j * 4 + 2);
        bits |= (mm.w != 0 ? 1u : 0u) << (j * 4 + 3);
    }

    // bit for column k0: lane (k0>>2)&63, bit (k0&3) + 4*(k0>>8)  (R6 mapping)
    unsigned int bk = (unsigned int)
        __builtin_amdgcn_ds_bpermute(((k0 >> 2) & 63) << 2, (int)bits);
    bool mb = (bk >> ((k0 & 3) + ((k0 >> 8) << 2))) & 1u;

    unsigned long long bm = __ballot(mb);

    // Z = sum of masked e over top-64 (butterfly; uniform result)
    float wz = mb ? e0 : 0.0f;
    #pragma unroll
    for (int off = 32; off > 0; off >>= 1)
        wz += __shfl_xor(wz, off, 64);

    if (lane == 0) { bmask[row] = bm; zrow[row] = wz; }
}

// ---------------- Kernel C: out[b,q,:] = sum_k p * value[b,k,:] ----------
// 512 threads = 8 waves; ONE WAVE = 4 ROWS of one batch; block = 32 rows.
// Top-64 V rows staged once per block in LDS (64KB, 2 blocks/CU). bm/Z are
// precomputed (bmz_kernel) -> 8 wave-uniform scalar loads; walk = fixed 64
// iterations, one ds_read_b128 feeds 4 accumulators, weights scalar-selected
// (s_cselect from SGPR u64). No gathers, no butterflies, no compaction.
__global__ __launch_bounds__(512)
void attn_kernel(const float* __restrict__ value, const int* __restrict__ mask,
                 const float2* __restrict__ pk, const float* __restrict__ rem,
                 const unsigned long long* __restrict__ bmask,
                 const float* __restrict__ zrow,
                 float* __restrict__ out) {
    __shared__ float lds_V[64 * ND];          // 64 KB: top-64 value rows

    const int wid  = threadIdx.x >> 6;        // 0..7
    const int lane = threadIdx.x & 63;
    const int row0 = blockIdx.x * 32 + wid * 4;   // wave's 4 rows
    const int b    = row0 >> 10;
    const int base = b << 10;

    const float4* vbase = (const float4*)(value + ((size_t)b << 10) * ND);
    const float2* pk_g  = pk + base;

    // top-64 metadata, lane-parallel (shared by all rows of the batch)
    float2 p0 = pk_g[lane];
    int   k0  = __float_as_int(p0.y);
    int   e0i = __float_as_int(p0.x);

    // precomputed per-row mask bits + Z: wave-uniform loads
    const unsigned long long bm0 = bmask[row0 + 0];
    const unsigned long long bm1 = bmask[row0 + 1];
    const unsigned long long bm2 = bmask[row0 + 2];
    const unsigned long long bm3 = bmask[row0 + 3];
    float z0 = zrow[row0 + 0], z1 = zrow[row0 + 1];
    float z2 = zrow[row0 + 2], z3 = zrow[row0 + 3];

    // stage top-64 V rows: wave w stages slots 8w..8w+7 (coalesced 1KB each)
    #pragma unroll
    for (int j = 0; j < 8; ++j) {
        int s   = wid * 8 + j;
        int ksr = __builtin_amdgcn_readlane(k0, s);    // uniform -> SGPR base
        ((float4*)lds_V)[s * 64 + lane] = vbase[(size_t)ksr * 64 + lane];
    }

    __syncthreads();   // lds_V ready

    // ---- walk: fixed 64 iterations over LDS; weights scalar-selected ----
    float4 acc0 = make_float4(0.f, 0.f, 0.f, 0.f);
    float4 acc1 = make_float4(0.f, 0.f, 0.f, 0.f);
    float4 acc2 = make_float4(0.f, 0.f, 0.f, 0.f);
    float4 acc3 = make_float4(0.f, 0.f, 0.f, 0.f);

    #pragma unroll 16
    for (int i = 0; i < 64; ++i) {
        float4 v = ((const float4*)lds_V)[i * 64 + lane];
        float ei = __int_as_float(__builtin_amdgcn_readlane(e0i, i));
        float w0 = ((bm0 >> i) & 1ull) ? ei : 0.0f;      // s_cselect
        float w1 = ((bm1 >> i) & 1ull) ? ei : 0.0f;
        float w2 = ((bm2 >> i) & 1ull) ? ei : 0.0f;
        float w3 = ((bm3 >> i) & 1ull) ? ei : 0.0f;
        acc0.x += w0 * v.x; acc0.y += w0 * v.y; acc0.z += w0 * v.z; acc0.w += w0 * v.w;
        acc1.x += w1 * v.x; acc1.y += w1 * v.y; acc1.z += w1 * v.z; acc1.w += w1 * v.w;
        acc2.x += w2 * v.x; acc2.y += w2 * v.y; acc2.z += w2 * v.z; acc2.w += w2 * v.w;
        acc3.x += w3 * v.x; acc3.y += w3 * v.y; acc3.z += w3 * v.z; acc3.w += w3 * v.w;
    }

    // ---- per-row epilogue: done check, rare deep chunks, store ----
    const float remv = rem[base + 63];

    auto finish_row = [&](int r, float4 acc, float Z) {
        const int* mrow = mask + (size_t)(row0 + r) * NL;
        bool done = (remv <= 1e-5f * Z);     // Z==0 -> rem>0 -> continue
        for (int c = 1; c < 16 && !done; ++c) {           // ~never taken
            float2 p = pk_g[c * 64 + lane];
            float e  = p.x;
            int   k  = __float_as_int(p.y);
            bool mb  = (mrow[k] != 0);
            float dz = mb ? e : 0.0f;
            #pragma unroll
            for (int off = 32; off > 0; off >>= 1)
                dz += __shfl_xor(dz, off, 64);
            unsigned long long bmx = __ballot(mb);
            int eI = __float_as_int(e);
            for (int i = 0; i < 64; ++i) {                // rolled: rare path
                float ei = __int_as_float(__builtin_amdgcn_readlane(eI, i));
                int   ki = __builtin_amdgcn_readlane(k, i);
                float w  = ((bmx >> i) & 1ull) ? ei : 0.0f;
                float4 v = vbase[(size_t)ki * 64 + lane];
                acc.x += w * v.x; acc.y += w * v.y;
                acc.z += w * v.z; acc.w += w * v.w;
            }
            Z += dz;
            done = (rem[base + c * 64 + 63] <= 1e-5f * Z);
        }
        float4* orow = (float4*)(out + (size_t)(row0 + r) * ND);
        if (Z > 0.0f) {
            float inv = 1.0f / Z;
            orow[lane] = make_float4(acc.x * inv, acc.y * inv,
                                     acc.z * inv, acc.w * inv);
        } else {
            // all-masked row: softmax over constant -1e9 -> uniform average
            float4 s = make_float4(0.f, 0.f, 0.f, 0.f);
            for (int k = 0; k < NL; ++k) {
                float4 v = vbase[(size_t)k * 64 + lane];
                s.x += v.x; s.y += v.y; s.z += v.z; s.w += v.w;
            }
            const float inv = 1.0f / (float)NL;
            orow[lane] = make_float4(s.x * inv, s.y * inv, s.z * inv, s.w * inv);
        }
    };
    finish_row(0, acc0, z0);
    finish_row(1, acc1, z1);
    finish_row(2, acc2, z2);
    finish_row(3, acc3, z3);
}

extern "C" void kernel_launch(void* const* d_in, const int* in_sizes, int n_in,
                              void* d_out, int out_size, void* d_ws, size_t ws_size,
                              hipStream_t stream) {
    // setup_inputs order: query, key, value, w, mask   (query unused!)
    const float* key   = (const float*)d_in[1];
    const float* value = (const float*)d_in[2];
    const float* w     = (const float*)d_in[3];
    const int*   mask  = (const int*)d_in[4];
    float*       outp  = (float*)d_out;

    float*  ks  = (float*)d_ws;                  // 16*1024 f32
    float2* pkb = (float2*)(ks + NB * NL);       // 16*1024 f32x2 (e, idx) bucket-desc
    float*  rem = (float*)(pkb + NB * NL);       // 16*1024 f32 suffix masses
    unsigned long long* bmask =
        (unsigned long long*)(rem + NB * NL);    // 16*1024 u64 top-64 mask bits
    float*  zrow = (float*)(bmask + NB * NL);    // 16*1024 f32 Z per row

    ks_kernel    <<<NB * NL / 4, 256, 0, stream>>>(key, w, ks);
    select_kernel<<<NB, 256, 0, stream>>>(ks, pkb, rem);
    bmz_kernel   <<<NB * NL / 4, 256, 0, stream>>>(mask, pkb, bmask, zrow);
    attn_kernel  <<<NB * NL / 32, 512, 0, stream>>>(value, mask, pkb, rem,
                                                    bmask, zrow, outp);
}

// Round 11
// 158.464 us; speedup vs baseline: 1.0596x; 1.0596x over previous
//
#include <hip/hip_runtime.h>
#include <math.h>

// Problem: B=16, LQ=1024, LK=1024, DK=256, DV=256, fp32 in/out, mask int32.
// Identity: softmax_k(q_s + k_s with mask) == mask-weighted softmax of k_s alone
// (q_s cancels; masked entries are exactly -1e9 -> weight 0). query never read.
// k_s ~ N(0,256) => softmax mass concentrates in top ~30-60 keys; chunk-0
// (top-64) provably terminates ~all rows (e_64 ~ e^-26 * Z << 1e-5 * Z).
//
// R1: counting-sort select. R2 (FAIL): scalar chains. R3-R7: per-row walks
// latency-bound (best R4 50us). R8 (FAIL): reg pipeline killed occupancy.
// R9 (159.8 total): 4 rows/wave LDS walk, mask gathers the bottleneck.
// R10 (167.9): bmz split ran both kernels fast but launch+gap ate the win.
//   Measured floor: 2x40us harness fills + ~35us dispatch gaps; kernel COUNT
//   is now first-order.
// R11: bmz merged back into attn with every isolated fix in place:
//   - R6 coalesced mask pattern (lane+64*j int4), 16 independent loads/wave
//     issued before any dependent op (R4's stall: walk did 3-4 LDS ops/iter);
//   - R9 walk: 1 ds_read_b128/iter feeds 4 rows, weights s_cselect'ed;
//   - bits->bpermute->ballot->butterfly once per row, overlapped with V-stage;
//   - one barrier; 512 thr x 512 blocks, 64KB LDS, 2 blocks/CU.
//   3 kernels total (ks, select, attn).

#define NB     16
#define NL     1024     // LQ == LK
#define ND     256      // DK == DV
#define NBKT   128      // buckets of width 1.0 in log-space

// ---------------- Kernel A: ks[b,k] = dot(key[b,k,:], w) -----------------
__global__ __launch_bounds__(256)
void ks_kernel(const float* __restrict__ key, const float* __restrict__ w,
               float* __restrict__ ks) {
    int wid  = threadIdx.x >> 6;
    int lane = threadIdx.x & 63;
    int row  = blockIdx.x * 4 + wid;               // 0 .. NB*NL-1
    const float4* krow = (const float4*)(key + (size_t)row * ND);
    float4 kv = krow[lane];
    float4 wv = ((const float4*)w)[lane];
    float p = kv.x * wv.x + kv.y * wv.y + kv.z * wv.z + kv.w * wv.w;
    #pragma unroll
    for (int off = 32; off > 0; off >>= 1)
        p += __shfl_xor(p, off, 64);
    if (lane == 0) ks[row] = p;
}

// ------- Kernel B: per batch: max, e=exp(ks-m), counting sort by -------
// ------- bucket floor(m-v), exact suffix mass at chunk boundaries -------
// 256 threads (4 waves), 4 entries/thread. Order within a bucket arbitrary;
// attn breaks on the EXACT suffix mass rem[] of the actual gathered order.
__global__ __launch_bounds__(256)
void select_kernel(const float* __restrict__ ks,
                   float2* __restrict__ pk, float* __restrict__ rem) {
    __shared__ float se[NL];       // gathered e values (bucket order)
    __shared__ int   cnt[NBKT];    // histogram
    __shared__ int   cur[NBKT];    // scan -> scatter cursors
    __shared__ float wred[4];      // per-wave max
    __shared__ float csum[16];     // per-chunk sums
    const int b    = blockIdx.x;
    const int t    = threadIdx.x;
    const int lane = t & 63;
    const int wid  = t >> 6;
    const float* ksb = ks + b * NL;

    if (t < NBKT) cnt[t] = 0;

    // 4 entries per thread, coalesced (stride 256)
    float v0 = ksb[t], v1 = ksb[t + 256], v2 = ksb[t + 512], v3 = ksb[t + 768];

    // block max: thread max4 -> wave shuffle reduce -> 4-way LDS combine
    float mx = fmaxf(fmaxf(v0, v1), fmaxf(v2, v3));
    #pragma unroll
    for (int off = 32; off > 0; off >>= 1)
        mx = fmaxf(mx, __shfl_xor(mx, off, 64));
    if (lane == 0) wred[wid] = mx;
    __syncthreads();                                        // #1 (also covers cnt=0)
    const float m = fmaxf(fmaxf(wred[0], wred[1]), fmaxf(wred[2], wred[3]));

    float e0 = __expf(v0 - m), e1 = __expf(v1 - m);
    float e2 = __expf(v2 - m), e3 = __expf(v3 - m);
    int b0 = (int)fminf(m - v0, (float)(NBKT - 1));
    int b1 = (int)fminf(m - v1, (float)(NBKT - 1));
    int b2 = (int)fminf(m - v2, (float)(NBKT - 1));
    int b3 = (int)fminf(m - v3, (float)(NBKT - 1));
    atomicAdd(&cnt[b0], 1); atomicAdd(&cnt[b1], 1);
    atomicAdd(&cnt[b2], 1); atomicAdd(&cnt[b3], 1);
    __syncthreads();                                        // #2

    // exclusive scan of cnt[128] by wave 0 via shuffles (no barriers inside)
    if (wid == 0) {
        int a  = cnt[lane];
        int b2v = cnt[lane + 64];
        int sa = a, sb = b2v;
        #pragma unroll
        for (int d = 1; d < 64; d <<= 1) {
            int na = __shfl_up(sa, d, 64);
            int nb = __shfl_up(sb, d, 64);
            if (lane >= d) { sa += na; sb += nb; }
        }
        int tot = __shfl(sa, 63, 64);
        sb += tot;
        cur[lane]      = sa - a;
        cur[lane + 64] = sb - b2v;
    }
    __syncthreads();                                        // #3

    // scatter (bijective: every entry gets a unique p in [0, NL))
    int p0 = atomicAdd(&cur[b0], 1);
    int p1 = atomicAdd(&cur[b1], 1);
    int p2 = atomicAdd(&cur[b2], 1);
    int p3 = atomicAdd(&cur[b3], 1);
    se[p0] = e0; pk[b * NL + p0] = make_float2(e0, __int_as_float(t));
    se[p1] = e1; pk[b * NL + p1] = make_float2(e1, __int_as_float(t + 256));
    se[p2] = e2; pk[b * NL + p2] = make_float2(e2, __int_as_float(t + 512));
    se[p3] = e3; pk[b * NL + p3] = make_float2(e3, __int_as_float(t + 768));
    __syncthreads();                                        // #4

    // per-chunk sums: wave w reduces chunks 4w..4w+3
    #pragma unroll
    for (int cc = 0; cc < 4; ++cc) {
        int chunk = wid * 4 + cc;
        float s = se[chunk * 64 + lane];
        #pragma unroll
        for (int off = 32; off > 0; off >>= 1)
            s += __shfl_xor(s, off, 64);
        if (lane == 0) csum[chunk] = s;
    }
    __syncthreads();                                        // #5

    // suffix masses at the 16 boundary slots attn actually reads
    if (t == 0) {
        float run = 0.0f;
        for (int c = 15; c >= 0; --c) {
            rem[b * NL + c * 64 + 63] = run;
            run += csum[c];
        }
    }
}

// ---------------- Kernel C: out[b,q,:] = sum_k p * value[b,k,:] ----------
// 512 threads = 8 waves; ONE WAVE = 4 ROWS of one batch; block = 32 rows.
// Prologue (all loads issued before dependent ops): 16 coalesced int4 mask
// loads (4/row, R6 pattern) + pk float2 + 8 uniform V-stage loads. Then per
// row: bits -> bpermute -> ballot (bm in SGPR) -> butterfly Z. One barrier.
// Walk = fixed 64 iters: one ds_read_b128 feeds 4 accumulators, weights
// scalar-selected. Epilogue per row (rare deep chunks + store).
__global__ __launch_bounds__(512)
void attn_kernel(const float* __restrict__ value, const int* __restrict__ mask,
                 const float2* __restrict__ pk, const float* __restrict__ rem,
                 float* __restrict__ out) {
    __shared__ float lds_V[64 * ND];          // 64 KB: top-64 value rows

    const int wid  = threadIdx.x >> 6;        // 0..7
    const int lane = threadIdx.x & 63;
    const int row0 = blockIdx.x * 32 + wid * 4;   // wave's 4 rows
    const int b    = row0 >> 10;
    const int base = b << 10;

    const float4* vbase = (const float4*)(value + ((size_t)b << 10) * ND);
    const float2* pk_g  = pk + base;

    // ---- prologue: issue all independent global loads first ----
    // mask rows, fully coalesced: load j covers columns 256j + 4*lane + (0..3)
    const int4* mr0 = (const int4*)(mask + (size_t)(row0 + 0) * NL);
    const int4* mr1 = (const int4*)(mask + (size_t)(row0 + 1) * NL);
    const int4* mr2 = (const int4*)(mask + (size_t)(row0 + 2) * NL);
    const int4* mr3 = (const int4*)(mask + (size_t)(row0 + 3) * NL);
    int4 a00 = mr0[lane], a01 = mr0[lane + 64], a02 = mr0[lane + 128], a03 = mr0[lane + 192];
    int4 a10 = mr1[lane], a11 = mr1[lane + 64], a12 = mr1[lane + 128], a13 = mr1[lane + 192];
    int4 a20 = mr2[lane], a21 = mr2[lane + 64], a22 = mr2[lane + 128], a23 = mr2[lane + 192];
    int4 a30 = mr3[lane], a31 = mr3[lane + 64], a32 = mr3[lane + 128], a33 = mr3[lane + 192];

    // top-64 metadata, lane-parallel (shared by all rows of the batch)
    float2 p0 = pk_g[lane];
    int   k0  = __float_as_int(p0.y);
    float e0  = p0.x;
    int   e0i = __float_as_int(e0);

    // stage top-64 V rows: wave w stages slots 8w..8w+7 (coalesced 1KB each)
    #pragma unroll
    for (int j = 0; j < 8; ++j) {
        int s   = wid * 8 + j;
        int ksr = __builtin_amdgcn_readlane(k0, s);    // uniform -> SGPR base
        ((float4*)lds_V)[s * 64 + lane] = vbase[(size_t)ksr * 64 + lane];
    }

    // ---- bits per row: bit (4j + c) = column 256j + 4*lane + c ----
    auto mkbits = [](int4 x0, int4 x1, int4 x2, int4 x3) -> unsigned int {
        unsigned int bits = 0;
        bits |= (x0.x != 0 ? 1u : 0u) << 0;  bits |= (x0.y != 0 ? 1u : 0u) << 1;
        bits |= (x0.z != 0 ? 1u : 0u) << 2;  bits |= (x0.w != 0 ? 1u : 0u) << 3;
        bits |= (x1.x != 0 ? 1u : 0u) << 4;  bits |= (x1.y != 0 ? 1u : 0u) << 5;
        bits |= (x1.z != 0 ? 1u : 0u) << 6;  bits |= (x1.w != 0 ? 1u : 0u) << 7;
        bits |= (x2.x != 0 ? 1u : 0u) << 8;  bits |= (x2.y != 0 ? 1u : 0u) << 9;
        bits |= (x2.z != 0 ? 1u : 0u) << 10; bits |= (x2.w != 0 ? 1u : 0u) << 11;
        bits |= (x3.x != 0 ? 1u : 0u) << 12; bits |= (x3.y != 0 ? 1u : 0u) << 13;
        bits |= (x3.z != 0 ? 1u : 0u) << 14; bits |= (x3.w != 0 ? 1u : 0u) << 15;
        return bits;
    };
    unsigned int bits0 = mkbits(a00, a01, a02, a03);
    unsigned int bits1 = mkbits(a10, a11, a12, a13);
    unsigned int bits2 = mkbits(a20, a21, a22, a23);
    unsigned int bits3 = mkbits(a30, a31, a32, a33);

    // bit for column k0: lane (k0>>2)&63, bit (k0&3) + 4*(k0>>8)  (R6 mapping)
    const int addr  = ((k0 >> 2) & 63) << 2;
    const int shift = (k0 & 3) + ((k0 >> 8) << 2);
    bool mb0 = (((unsigned int)__builtin_amdgcn_ds_bpermute(addr, (int)bits0)) >> shift) & 1u;
    bool mb1 = (((unsigned int)__builtin_amdgcn_ds_bpermute(addr, (int)bits1)) >> shift) & 1u;
    bool mb2 = (((unsigned int)__builtin_amdgcn_ds_bpermute(addr, (int)bits2)) >> shift) & 1u;
    bool mb3 = (((unsigned int)__builtin_amdgcn_ds_bpermute(addr, (int)bits3)) >> shift) & 1u;
    unsigned long long bm0 = __ballot(mb0);
    unsigned long long bm1 = __ballot(mb1);
    unsigned long long bm2 = __ballot(mb2);
    unsigned long long bm3 = __ballot(mb3);

    // Z per row: butterfly of mask-selected e (uniform result)
    auto zsum = [&](bool mb) -> float {
        float wz = mb ? e0 : 0.0f;
        #pragma unroll
        for (int off = 32; off > 0; off >>= 1)
            wz += __shfl_xor(wz, off, 64);
        return wz;
    };
    float z0 = zsum(mb0), z1 = zsum(mb1), z2 = zsum(mb2), z3 = zsum(mb3);

    __syncthreads();   // lds_V ready

    // ---- walk: fixed 64 iterations over LDS; weights scalar-selected ----
    float4 acc0 = make_float4(0.f, 0.f, 0.f, 0.f);
    float4 acc1 = make_float4(0.f, 0.f, 0.f, 0.f);
    float4 acc2 = make_float4(0.f, 0.f, 0.f, 0.f);
    float4 acc3 = make_float4(0.f, 0.f, 0.f, 0.f);

    #pragma unroll 16
    for (int i = 0; i < 64; ++i) {
        float4 v = ((const float4*)lds_V)[i * 64 + lane];
        float ei = __int_as_float(__builtin_amdgcn_readlane(e0i, i));
        float w0 = ((bm0 >> i) & 1ull) ? ei : 0.0f;      // s_cselect
        float w1 = ((bm1 >> i) & 1ull) ? ei : 0.0f;
        float w2 = ((bm2 >> i) & 1ull) ? ei : 0.0f;
        float w3 = ((bm3 >> i) & 1ull) ? ei : 0.0f;
        acc0.x += w0 * v.x; acc0.y += w0 * v.y; acc0.z += w0 * v.z; acc0.w += w0 * v.w;
        acc1.x += w1 * v.x; acc1.y += w1 * v.y; acc1.z += w1 * v.z; acc1.w += w1 * v.w;
        acc2.x += w2 * v.x; acc2.y += w2 * v.y; acc2.z += w2 * v.z; acc2.w += w2 * v.w;
        acc3.x += w3 * v.x; acc3.y += w3 * v.y; acc3.z += w3 * v.z; acc3.w += w3 * v.w;
    }

    // ---- per-row epilogue: done check, rare deep chunks, store ----
    const float remv = rem[base + 63];

    auto finish_row = [&](int r, float4 acc, float Z) {
        const int* mrow = mask + (size_t)(row0 + r) * NL;
        bool done = (remv <= 1e-5f * Z);     // Z==0 -> rem>0 -> continue
        for (int c = 1; c < 16 && !done; ++c) {           // ~never taken
            float2 p = pk_g[c * 64 + lane];
            float e  = p.x;
            int   k  = __float_as_int(p.y);
            bool mb  = (mrow[k] != 0);
            float dz = mb ? e : 0.0f;
            #pragma unroll
            for (int off = 32; off > 0; off >>= 1)
                dz += __shfl_xor(dz, off, 64);
            unsigned long long bmx = __ballot(mb);
            int eI = __float_as_int(e);
            for (int i = 0; i < 64; ++i) {                // rolled: rare path
                float ei = __int_as_float(__builtin_amdgcn_readlane(eI, i));
                int   ki = __builtin_amdgcn_readlane(k, i);
                float w  = ((bmx >> i) & 1ull) ? ei : 0.0f;
                float4 v = vbase[(size_t)ki * 64 + lane];
                acc.x += w * v.x; acc.y += w * v.y;
                acc.z += w * v.z; acc.w += w * v.w;
            }
            Z += dz;
            done = (rem[base + c * 64 + 63] <= 1e-5f * Z);
        }
        float4* orow = (float4*)(out + (size_t)(row0 + r) * ND);
        if (Z > 0.0f) {
            float inv = 1.0f / Z;
            orow[lane] = make_float4(acc.x * inv, acc.y * inv,
                                     acc.z * inv, acc.w * inv);
        } else {
            // all-masked row: softmax over constant -1e9 -> uniform average
            float4 s = make_float4(0.f, 0.f, 0.f, 0.f);
            for (int k = 0; k < NL; ++k) {
                float4 v = vbase[(size_t)k * 64 + lane];
                s.x += v.x; s.y += v.y; s.z += v.z; s.w += v.w;
            }
            const float inv = 1.0f / (float)NL;
            orow[lane] = make_float4(s.x * inv, s.y * inv, s.z * inv, s.w * inv);
        }
    };
    finish_row(0, acc0, z0);
    finish_row(1, acc1, z1);
    finish_row(2, acc2, z2);
    finish_row(3, acc3, z3);
}

extern "C" void kernel_launch(void* const* d_in, const int* in_sizes, int n_in,
                              void* d_out, int out_size, void* d_ws, size_t ws_size,
                              hipStream_t stream) {
    // setup_inputs order: query, key, value, w, mask   (query unused!)
    const float* key   = (const float*)d_in[1];
    const float* value = (const float*)d_in[2];
    const float* w     = (const float*)d_in[3];
    const int*   mask  = (const int*)d_in[4];
    float*       outp  = (float*)d_out;

    float*  ks  = (float*)d_ws;                  // 16*1024 f32
    float2* pkb = (float2*)(ks + NB * NL);       // 16*1024 f32x2 (e, idx) bucket-desc
    float*  rem = (float*)(pkb + NB * NL);       // 16*1024 f32 suffix masses

    ks_kernel    <<<NB * NL / 4, 256, 0, stream>>>(key, w, ks);
    select_kernel<<<NB, 256, 0, stream>>>(ks, pkb, rem);
    attn_kernel  <<<NB * NL / 32, 512, 0, stream>>>(value, mask, pkb, rem, outp);
}